// Round 1
// baseline (312.334 us; speedup 1.0000x reference)
//
#include <hip/hip_runtime.h>

#define NN 64
#define CC 128
#define TT 2048
#define SS 9
#define PAD 4
#define EPSF 1e-5f

// Per-channel conv accumulator for (n,c) at time t:
//   acc = sum_{s=0..8} cw[c*9+s] * X(n, c+s-4, t - ((c+s-4)%9 - 4))
// with X zero outside channel [0,C) or time [0,T).
__device__ __forceinline__ float conv_at(const float* __restrict__ xn,
                                         const float* __restrict__ cw,
                                         int c, int t)
{
    float acc = 0.f;
#pragma unroll
    for (int s = 0; s < SS; ++s) {
        int c2 = c + s - PAD;                 // block-uniform
        if (c2 >= 0 && c2 < CC) {             // block-uniform branch
            int sh = (c2 % SS) - PAD;         // block-uniform
            int tt = t - sh;                  // per-lane
            if (tt >= 0 && tt < TT)
                acc += cw[c * SS + s] * xn[c2 * TT + tt];
        }
    }
    return acc;
}

__global__ __launch_bounds__(256) void conv_stats_kernel(
    const float* __restrict__ x, const float* __restrict__ cw,
    float* __restrict__ stats)
{
    const int blk = blockIdx.x;
    const int c = blk & (CC - 1);
    const int n = blk >> 7;                   // C == 128
    const float* xn = x + (size_t)n * CC * TT;

    float sum = 0.f, sumsq = 0.f;
    for (int t = threadIdx.x; t < TT; t += 256) {
        float acc = conv_at(xn, cw, c, t);
        sum += acc;
        sumsq += acc * acc;
    }

    // wave (64-lane) shuffle reduce, then LDS across the 4 waves
#pragma unroll
    for (int off = 32; off > 0; off >>= 1) {
        sum   += __shfl_down(sum, off, 64);
        sumsq += __shfl_down(sumsq, off, 64);
    }
    __shared__ float sa[4], sb[4];
    const int lane = threadIdx.x & 63;
    const int wid  = threadIdx.x >> 6;
    if (lane == 0) { sa[wid] = sum; sb[wid] = sumsq; }
    __syncthreads();
    if (threadIdx.x == 0) {
        float bs = sa[0] + sa[1] + sa[2] + sa[3];
        float bq = sb[0] + sb[1] + sb[2] + sb[3];
        atomicAdd(&stats[c], bs);
        atomicAdd(&stats[CC + c], bq);
    }
}

__global__ __launch_bounds__(256) void conv_norm_kernel(
    const float* __restrict__ x, const float* __restrict__ cw,
    const float* __restrict__ gamma, const float* __restrict__ beta,
    const float* __restrict__ stats, float* __restrict__ out)
{
    const int blk = blockIdx.x;
    const int c = blk & (CC - 1);
    const int n = blk >> 7;
    const float* xn = x + (size_t)n * CC * TT;

    const float inv_cnt = 1.0f / (float)(NN * TT);
    const float mean = stats[c] * inv_cnt;
    const float var  = stats[CC + c] * inv_cnt - mean * mean;
    const float inv  = rsqrtf(var + EPSF);
    const float g = gamma[c] * inv;
    const float b = beta[c] - mean * g;

    float* on = out + (size_t)(n * CC + c) * TT;
    for (int t = threadIdx.x; t < TT; t += 256) {
        float acc = conv_at(xn, cw, c, t);
        float v = acc * g + b;
        on[t] = v > 0.f ? v : 0.f;
    }
}

extern "C" void kernel_launch(void* const* d_in, const int* in_sizes, int n_in,
                              void* d_out, int out_size, void* d_ws, size_t ws_size,
                              hipStream_t stream)
{
    const float* x     = (const float*)d_in[0];
    const float* cw    = (const float*)d_in[1];
    const float* gamma = (const float*)d_in[2];
    const float* beta  = (const float*)d_in[3];
    float* out   = (float*)d_out;
    float* stats = (float*)d_ws;   // [0..C): sum, [C..2C): sumsq

    hipMemsetAsync(stats, 0, 2 * CC * sizeof(float), stream);
    conv_stats_kernel<<<NN * CC, 256, 0, stream>>>(x, cw, stats);
    conv_norm_kernel<<<NN * CC, 256, 0, stream>>>(x, cw, gamma, beta, stats, out);
}